// Round 9
// baseline (118.310 us; speedup 1.0000x reference)
//
#include <hip/hip_runtime.h>
#include <math.h>

#define SEQ 512
#define HID 256
#define NH 8
#define DH 32
#define PI_F 3.14159265358979323846f
#define SCALE_F 0.17677669529663687f  /* 1/sqrt(32) */
#define LOG2E_F 1.4426950408889634f

// ws layout (float offsets): raw (pre-activation, pre-bias) projections
#define OFF_Q 0
#define OFF_K 131072
#define OFF_V 262144

// one 64-wide K-chunk of a 64x64 tile: acc += A[r0..][k0..k0+64) * W[c0..][k0..]^T
// LDS: A natural [r][k] stride 68 (<=2-way), W transposed [k][c^swz], XOR-4
// swizzle keeps transpose-write and b128 compute-read <=2-way (free, m136).
__device__ __forceinline__ void gemm_chunk(
    const float* __restrict__ A, const float* __restrict__ W,
    int r0, int c0, int k0, int tid, float (&acc)[4][4],
    float* __restrict__ xs, float* __restrict__ wts)
{
#pragma unroll
    for (int it = 0; it < 4; it++) {
        int idx = tid + it * 256;
        int rr = idx >> 4, f4 = idx & 15;
        float4 av = *(const float4*)(A + (r0 + rr) * HID + k0 + 4 * f4);
        *(float4*)&xs[rr * 68 + 4 * f4] = av;
        float4 wv = *(const float4*)(W + (c0 + rr) * HID + k0 + 4 * f4);
        int cw = rr ^ ((f4 & 7) << 2);
        wts[(4 * f4 + 0) * 64 + cw] = wv.x;
        wts[(4 * f4 + 1) * 64 + cw] = wv.y;
        wts[(4 * f4 + 2) * 64 + cw] = wv.z;
        wts[(4 * f4 + 3) * 64 + cw] = wv.w;
    }
    __syncthreads();
    const int rg = tid >> 4, cgi = tid & 15;
#pragma unroll
    for (int g = 0; g < 16; g++) {
        float xfa[4][4], wfa[4][4];
#pragma unroll
        for (int i = 0; i < 4; i++) {
            float4 xv = *(const float4*)&xs[(4 * rg + i) * 68 + 4 * g];
            xfa[i][0] = xv.x; xfa[i][1] = xv.y; xfa[i][2] = xv.z; xfa[i][3] = xv.w;
        }
        const int sw = (g & 7) << 2;
#pragma unroll
        for (int m = 0; m < 4; m++) {
            float4 wv = *(const float4*)&wts[(4 * g + m) * 64 + ((4 * cgi) ^ sw)];
            wfa[m][0] = wv.x; wfa[m][1] = wv.y; wfa[m][2] = wv.z; wfa[m][3] = wv.w;
        }
#pragma unroll
        for (int m = 0; m < 4; m++)
#pragma unroll
            for (int i = 0; i < 4; i++)
#pragma unroll
                for (int j = 0; j < 4; j++)
                    acc[i][j] = fmaf(xfa[i][m], wfa[m][j], acc[i][j]);
    }
    __syncthreads();
}

// ---- K1: QKV split-K4 GEMM, atomic fan-in to zeroed raw buffers ----------
// grid 384 = which(3) x tile(32: rt8 x ct4) x ks(4). Raw partials (no bias,
// no activation) atomicAdd'ed; K2 applies bias+activation on the fly.
// Also seeds out[] with bo for K2's atomic out-projection.
__global__ __launch_bounds__(256) void gemm_qkv_splitk(
    const float* __restrict__ x,
    const float* __restrict__ wq, const float* __restrict__ wk,
    const float* __restrict__ wv, const float* __restrict__ bo,
    float* __restrict__ ws, float* __restrict__ out)
{
    const int b = blockIdx.x;
    const int which = b >> 7;          // 0..2
    const int t = (b >> 2) & 31;       // tile 0..31: rt(8) x ct(4)
    const int ks = b & 3;
    const int r0 = (t >> 2) * 64, c0 = (t & 3) * 64, k0 = ks * 64;
    const float* W = (which == 0) ? wq : (which == 1) ? wk : wv;

    // seed out with bias (any block subset; all 384 cover it grid-stride)
    for (int idx = b * 256 + threadIdx.x; idx < SEQ * HID; idx += 384 * 256)
        out[idx] = bo[idx & 255];

    __shared__ float xs[64 * 68];
    __shared__ float wts[64 * 64];

    const int tid = threadIdx.x;
    float acc[4][4];
#pragma unroll
    for (int i = 0; i < 4; i++)
#pragma unroll
        for (int j = 0; j < 4; j++) acc[i][j] = 0.f;

    gemm_chunk(x, W, r0, c0, k0, tid, acc, xs, wts);

    float* R = ws + which * 131072;
    const int rg = tid >> 4, cgi = tid & 15;
#pragma unroll
    for (int i = 0; i < 4; i++)
#pragma unroll
        for (int j = 0; j < 4; j++)
            atomicAdd(&R[(r0 + 4 * rg + i) * HID + c0 + 4 * cgi + j], acc[i][j]);
}

// ---- K2: activations + wave attention + fused out-projection -------------
// grid 512: b -> (i8 = b>>3, h = b&7); thread = (il = tid>>5, d = tid&31).
// Reads raw q,k,v; bias+activation per thread. v-bias folds out:
// ctx = num/den + bv[col]. Then ctx slice x wo slice -> atomicAdd into out.
__global__ __launch_bounds__(256) void wave_attn_out(
    const float* __restrict__ ws, const float* __restrict__ wo,
    const float* __restrict__ bq, const float* __restrict__ bk,
    const float* __restrict__ bv, float* __restrict__ out)
{
    const int b  = blockIdx.x;
    const int i8 = b >> 3;
    const int h  = b & 7;
    const int il = threadIdx.x >> 5;
    const int d  = threadIdx.x & 31;
    const int i  = i8 * 8 + il;
    const int col = h * DH + d;
    const int tid = threadIdx.x;

    __shared__ float wo_l[256][33];
    __shared__ float ctx_l[8][33];

    // stage wo[:, h*32 .. h*32+32) -> wo_l[c][kk], coalesced
#pragma unroll
    for (int it = 0; it < 8; it++) {
        int idx = tid + it * 256;
        int c = idx >> 3, f = idx & 7;
        float4 wv = *(const float4*)(wo + c * HID + h * DH + 4 * f);
        wo_l[c][4 * f + 0] = wv.x;
        wo_l[c][4 * f + 1] = wv.y;
        wo_l[c][4 * f + 2] = wv.z;
        wo_l[c][4 * f + 3] = wv.w;
    }

    const float qr = ws[OFF_Q + i * HID + col] + bq[col];
    const float kr = ws[OFF_K + i * HID + col] + bk[col];
    const float bvc = bv[col];
    const float vr = ws[OFF_V + i * HID + col] + bvc;

    const float w  = PI_F / (1.f + expf(-qr));                    // omega
    const float aL = (SCALE_F * LOG2E_F) / (1.f + expf(-kr));     // amp*scale*log2e
    const float ph = PI_F * tanhf(vr);                            // phase
    const float* vcol = ws + OFF_V + col;                         // raw v

    float sw_, cw;
    sincosf(w, &sw_, &cw);
    float c2 = cw * cw - sw_ * sw_, s2 = 2.f * sw_ * cw;
    float c4 = c2 * c2 - s2 * s2,   s4 = 2.f * s2 * c2;

    float th0 = fmaf(w, (float)i, ph);
    float s0, cc0;
    sincosf(th0, &s0, &cc0);

    float pc[4], psn[4];
    pc[0] = cc0; psn[0] = s0;
#pragma unroll
    for (int k = 1; k < 4; k++) {       // rotate by -w per step
        float nc = pc[k - 1] * cw + psn[k - 1] * sw_;
        float ns = psn[k - 1] * cw - pc[k - 1] * sw_;
        pc[k] = nc; psn[k] = ns;
    }
    float p[4], q[4], den[4], num[4];
#pragma unroll
    for (int k = 0; k < 4; k++) {
        p[k] = aL * pc[k]; q[k] = aL * psn[k];
        den[k] = 0.f; num[k] = 0.f;
    }

#pragma unroll 4
    for (int t = 0; t < SEQ / 4; t++) {
        float v0 = vcol[(4 * t + 0) * HID];
        float v1 = vcol[(4 * t + 1) * HID];
        float v2v = vcol[(4 * t + 2) * HID];
        float v3 = vcol[(4 * t + 3) * HID];
        float e0 = __builtin_amdgcn_exp2f(p[0]);
        float e1 = __builtin_amdgcn_exp2f(p[1]);
        float e2 = __builtin_amdgcn_exp2f(p[2]);
        float e3 = __builtin_amdgcn_exp2f(p[3]);
        den[0] += e0; den[1] += e1; den[2] += e2; den[3] += e3;
        num[0] = fmaf(e0, v0, num[0]);
        num[1] = fmaf(e1, v1, num[1]);
        num[2] = fmaf(e2, v2v, num[2]);
        num[3] = fmaf(e3, v3, num[3]);
#pragma unroll
        for (int k = 0; k < 4; k++) {
            float np = p[k] * c4 + q[k] * s4;   // angle -= 4w
            float nq = q[k] * c4 - p[k] * s4;
            p[k] = np; q[k] = nq;
        }
    }
    float denom = (den[0] + den[1]) + (den[2] + den[3]);
    float numer = (num[0] + num[1]) + (num[2] + num[3]);

    __syncthreads();                    // wo_l staged; ctx_l safe to write
    ctx_l[il][d] = numer / denom + bvc; // fold v-bias back in
    __syncthreads();

    float ctx_r[32];
#pragma unroll
    for (int kk = 0; kk < 32; kk++) ctx_r[kk] = ctx_l[il][kk];
#pragma unroll
    for (int m = 0; m < 8; m++) {
        const int c = d + 32 * m;
        float s = 0.f;
#pragma unroll
        for (int kk = 0; kk < 32; kk++)
            s = fmaf(ctx_r[kk], wo_l[c][kk], s);
        atomicAdd(&out[i * HID + c], s);
    }
}

extern "C" void kernel_launch(void* const* d_in, const int* in_sizes, int n_in,
                              void* d_out, int out_size, void* d_ws, size_t ws_size,
                              hipStream_t stream) {
    const float* x  = (const float*)d_in[0];
    const float* wq = (const float*)d_in[1];
    const float* bq = (const float*)d_in[2];
    const float* wk = (const float*)d_in[3];
    const float* bk = (const float*)d_in[4];
    const float* wv = (const float*)d_in[5];
    const float* bv = (const float*)d_in[6];
    const float* wo = (const float*)d_in[7];
    const float* bo = (const float*)d_in[8];

    float* ws  = (float*)d_ws;
    float* out = (float*)d_out;

    hipMemsetAsync(ws, 0, 3 * SEQ * HID * sizeof(float), stream);
    hipLaunchKernelGGL(gemm_qkv_splitk, dim3(384), dim3(256), 0, stream,
                       x, wq, wk, wv, bo, ws, out);
    hipLaunchKernelGGL(wave_attn_out, dim3(512), dim3(256), 0, stream,
                       ws, wo, bq, bk, bv, out);
}